// Round 3
// baseline (128.369 us; speedup 1.0000x reference)
//
#include <hip/hip_runtime.h>

// x [8,128,96,96] fp32, W [384,128] fp32, out [8,128,96,96] fp32.
#define NB     8
#define CIN    128
#define HEADS  4
#define DHEAD  32
#define HDIM   96
#define WDIM   96
#define HW     9216
#define TP     32    // positions per stage-1 block

typedef __bf16 bf16x8 __attribute__((ext_vector_type(8)));
typedef float  f32x4  __attribute__((ext_vector_type(4)));

__device__ __forceinline__ unsigned f2bf(float f) {
  unsigned u = __float_as_uint(f);
  return (u + 0x7fffu + ((u >> 16) & 1u)) >> 16;   // RNE
}
__device__ __forceinline__ unsigned pack2(float a, float b) {
  return f2bf(a) | (f2bf(b) << 16);
}
__device__ __forceinline__ float bflo(unsigned u) { return __uint_as_float(u << 16); }
__device__ __forceinline__ float bfhi(unsigned u) { return __uint_as_float(u & 0xffff0000u); }

// ---------------------------------------------------------------------------
// Prep: pack W [384][128] fp32 -> A-fragment-ordered bf16 (16x16x32 MFMA).
// Frag (ot,kb): lane l holds A[o=ot*16+(l&15)][c=kb*32+(l>>4)*8+j], j=0..7.
// ---------------------------------------------------------------------------
__global__ __launch_bounds__(256) void wpack_kernel(const float* __restrict__ W,
                                                    uint4* __restrict__ Wf) {
  const int u = blockIdx.x * 256 + threadIdx.x;   // 24 ot * 4 kb * 64 lanes
  const int lane = u & 63, kb = (u >> 6) & 3, ot = u >> 8;
  const int o = ot * 16 + (lane & 15);
  const int c0 = kb * 32 + (lane >> 4) * 8;
  const float4* w = (const float4*)(W + (size_t)o * CIN + c0);
  float4 w0 = w[0], w1 = w[1];
  uint4 r;
  r.x = pack2(w0.x, w0.y); r.y = pack2(w0.z, w0.w);
  r.z = pack2(w1.x, w1.y); r.w = pack2(w1.z, w1.w);
  Wf[u] = r;
}

// ---------------------------------------------------------------------------
// Stage 1: QKV projection via bf16 MFMA. C[o][p] = sum_c W[o][c] * x[c][p].
// qkv layout: [which(3)][b][g(4)][p(9216)][d(32)] bf16.
// TP=32 -> 2304 blocks (9/CU) for full occupancy.
// ---------------------------------------------------------------------------
__global__ __launch_bounds__(256) void qkv_kernel(const float* __restrict__ x,
                                                  const uint4* __restrict__ Wf,
                                                  unsigned short* __restrict__ qkvb) {
  __shared__ uint4 xs[8 * 64];          // [pt(2)*4+kb][q*16+n], 8 KB
  const int b  = blockIdx.y;
  const int p0 = blockIdx.x * TP;
  const int t  = threadIdx.x;

  // ---- stage x tile [128 c][32 p] as bf16 B-frags ----
#pragma unroll
  for (int i = 0; i < 2; ++i) {
    const int slot = i * 256 + t;        // 0..511 = 16 c-octets * 32 px
    const int px = slot & 31, oct = slot >> 5;
    const int c0 = oct * 8;
    const float* xb = x + ((size_t)b * CIN + c0) * HW + p0 + px;
    float f[8];
#pragma unroll
    for (int j = 0; j < 8; ++j) f[j] = xb[(size_t)j * HW];   // 2x128B per instr
    uint4 r;
    r.x = pack2(f[0], f[1]); r.y = pack2(f[2], f[3]);
    r.z = pack2(f[4], f[5]); r.w = pack2(f[6], f[7]);
    const int pt = px >> 4, n = px & 15, kb = oct >> 2, q = oct & 3;
    xs[(pt * 4 + kb) * 64 + q * 16 + n] = r;
  }
  __syncthreads();

  const int wv = t >> 6, lane = t & 63;
  const int colp = lane & 15, quad = lane >> 4;
#pragma unroll
  for (int it = 0; it < 6; ++it) {
    const int ot = wv * 6 + it;
    bf16x8 afrag[4];
#pragma unroll
    for (int kb = 0; kb < 4; ++kb) {
      uint4 tmp = Wf[(ot * 4 + kb) * 64 + lane];   // L2-hot
      afrag[kb] = *(bf16x8*)&tmp;
    }
    const int o0 = ot * 16 + quad * 4;
    const int which = o0 >> 7, g = (o0 & 127) >> 5, d0 = o0 & 31;
    unsigned short* dst = qkvb
        + (((size_t)(which * NB + b) * HEADS + g) * HW) * DHEAD + d0;
#pragma unroll
    for (int pt = 0; pt < 2; ++pt) {
      f32x4 acc = {0.f, 0.f, 0.f, 0.f};
#pragma unroll
      for (int kb = 0; kb < 4; ++kb) {
        bf16x8 bfrag = *(bf16x8*)&xs[(pt * 4 + kb) * 64 + lane];
        acc = __builtin_amdgcn_mfma_f32_16x16x32_bf16(afrag[kb], bfrag, acc, 0, 0, 0);
      }
      const int pp = p0 + pt * 16 + colp;
      uint2 st;
      st.x = pack2(acc[0], acc[1]);
      st.y = pack2(acc[2], acc[3]);
      *(uint2*)(dst + (size_t)pp * DHEAD) = st;
    }
  }
}

// ---------------------------------------------------------------------------
// Stage 2: 3x3 neighborhood attention, 2 threads per pixel (d split 16+16).
// Branch-free: clamped loads + predicated logits (OOB logit == 0 exactly,
// matching zero-padded K; OOB v weight == 0).
// blockDim (64,4): lane = wq + 32*dh; __shfl_xor(.,32) combines half-dots.
// ---------------------------------------------------------------------------
__global__ __launch_bounds__(256) void attn_kernel(const unsigned short* __restrict__ qkvb,
                                                   float* __restrict__ out) {
  const int tx = threadIdx.x;                 // 0..63 (one wave)
  const int wq = tx & 31, dh = tx >> 5;
  const int w  = blockIdx.x * 32 + wq;
  const int h  = blockIdx.y * 4 + threadIdx.y;
  const int bg = blockIdx.z;                  // b*4+g
  const int b  = bg >> 2, g = bg & 3;

  const size_t plane = (size_t)HW * DHEAD;    // ushorts
  const unsigned short* Qb = qkvb + (size_t)bg * plane;
  const unsigned short* Kb = qkvb + (size_t)(32 + bg) * plane;
  const unsigned short* Vb = qkvb + (size_t)(64 + bg) * plane;
  const int p = h * WDIM + w;

  float q[16];
  {
    const uint4* qp = (const uint4*)(Qb + (size_t)p * DHEAD + dh * 16);
    uint4 u0 = qp[0], u1 = qp[1];
    q[0] = bflo(u0.x); q[1] = bfhi(u0.x); q[2] = bflo(u0.y); q[3] = bfhi(u0.y);
    q[4] = bflo(u0.z); q[5] = bfhi(u0.z); q[6] = bflo(u0.w); q[7] = bfhi(u0.w);
    q[8]  = bflo(u1.x); q[9]  = bfhi(u1.x); q[10] = bflo(u1.y); q[11] = bfhi(u1.y);
    q[12] = bflo(u1.z); q[13] = bfhi(u1.z); q[14] = bflo(u1.w); q[15] = bfhi(u1.w);
  }

  float att[9];
#pragma unroll
  for (int dy = -1; dy <= 1; ++dy) {
    const int hh = h + dy;
    const int hc = min(max(hh, 0), HDIM - 1);
    const bool rowOK = (unsigned)hh < (unsigned)HDIM;
#pragma unroll
    for (int dx = -1; dx <= 1; ++dx) {
      const int nn = (dy + 1) * 3 + (dx + 1);
      const int ww = w + dx;
      const int wc = min(max(ww, 0), WDIM - 1);
      const bool ok = rowOK && ((unsigned)ww < (unsigned)WDIM);
      const int pn = hc * WDIM + wc;
      const uint4* kp = (const uint4*)(Kb + (size_t)pn * DHEAD + dh * 16);
      uint4 k0 = kp[0], k1 = kp[1];
      float dot = 0.f;
      dot = fmaf(q[0], bflo(k0.x), dot);  dot = fmaf(q[1], bfhi(k0.x), dot);
      dot = fmaf(q[2], bflo(k0.y), dot);  dot = fmaf(q[3], bfhi(k0.y), dot);
      dot = fmaf(q[4], bflo(k0.z), dot);  dot = fmaf(q[5], bfhi(k0.z), dot);
      dot = fmaf(q[6], bflo(k0.w), dot);  dot = fmaf(q[7], bfhi(k0.w), dot);
      dot = fmaf(q[8],  bflo(k1.x), dot); dot = fmaf(q[9],  bfhi(k1.x), dot);
      dot = fmaf(q[10], bflo(k1.y), dot); dot = fmaf(q[11], bfhi(k1.y), dot);
      dot = fmaf(q[12], bflo(k1.z), dot); dot = fmaf(q[13], bfhi(k1.z), dot);
      dot = fmaf(q[14], bflo(k1.w), dot); dot = fmaf(q[15], bfhi(k1.w), dot);
      dot += __shfl_xor(dot, 32);                     // combine d halves
      att[nn] = ok ? dot * 0.17677669529663687f : 0.f; // OOB logit = 0 (zero-pad)
    }
  }

  float m = att[0];
#pragma unroll
  for (int nn = 1; nn < 9; ++nn) m = fmaxf(m, att[nn]);
  float s = 0.f;
#pragma unroll
  for (int nn = 0; nn < 9; ++nn) { att[nn] = __expf(att[nn] - m); s += att[nn]; }
  const float inv = 1.0f / s;

  float acc[16];
#pragma unroll
  for (int i = 0; i < 16; ++i) acc[i] = 0.f;
#pragma unroll
  for (int dy = -1; dy <= 1; ++dy) {
    const int hh = h + dy;
    const int hc = min(max(hh, 0), HDIM - 1);
    const bool rowOK = (unsigned)hh < (unsigned)HDIM;
#pragma unroll
    for (int dx = -1; dx <= 1; ++dx) {
      const int nn = (dy + 1) * 3 + (dx + 1);
      const int ww = w + dx;
      const int wc = min(max(ww, 0), WDIM - 1);
      const bool ok = rowOK && ((unsigned)ww < (unsigned)WDIM);
      const int pn = hc * WDIM + wc;
      const float wn = ok ? att[nn] * inv : 0.f;       // OOB v contributes 0
      const uint4* vp = (const uint4*)(Vb + (size_t)pn * DHEAD + dh * 16);
      uint4 v0 = vp[0], v1 = vp[1];
      acc[0] = fmaf(wn, bflo(v0.x), acc[0]);  acc[1] = fmaf(wn, bfhi(v0.x), acc[1]);
      acc[2] = fmaf(wn, bflo(v0.y), acc[2]);  acc[3] = fmaf(wn, bfhi(v0.y), acc[3]);
      acc[4] = fmaf(wn, bflo(v0.z), acc[4]);  acc[5] = fmaf(wn, bfhi(v0.z), acc[5]);
      acc[6] = fmaf(wn, bflo(v0.w), acc[6]);  acc[7] = fmaf(wn, bfhi(v0.w), acc[7]);
      acc[8]  = fmaf(wn, bflo(v1.x), acc[8]);  acc[9]  = fmaf(wn, bfhi(v1.x), acc[9]);
      acc[10] = fmaf(wn, bflo(v1.y), acc[10]); acc[11] = fmaf(wn, bfhi(v1.y), acc[11]);
      acc[12] = fmaf(wn, bflo(v1.z), acc[12]); acc[13] = fmaf(wn, bfhi(v1.z), acc[13]);
      acc[14] = fmaf(wn, bflo(v1.w), acc[14]); acc[15] = fmaf(wn, bfhi(v1.w), acc[15]);
    }
  }

  // out [b][C=128][96][96]; channel = g*32 + dh*16 + i; lanes along w -> 128B rows
  float* ob = out + ((size_t)b * CIN + (size_t)g * DHEAD + dh * 16) * HW + p;
#pragma unroll
  for (int i = 0; i < 16; ++i) ob[(size_t)i * HW] = acc[i];
}

extern "C" void kernel_launch(void* const* d_in, const int* in_sizes, int n_in,
                              void* d_out, int out_size, void* d_ws, size_t ws_size,
                              hipStream_t stream) {
  (void)in_sizes; (void)n_in; (void)out_size; (void)ws_size;
  const float* x = (const float*)d_in[0];   // [8,128,96,96]
  const float* W = (const float*)d_in[1];   // [384,128]
  float* out = (float*)d_out;

  const size_t qkv_ushorts = (size_t)3 * NB * HEADS * HW * DHEAD;  // 56.6 MB
  unsigned short* qkvb = (unsigned short*)d_ws;
  uint4* Wf = (uint4*)((char*)d_ws + qkv_ushorts * 2);             // +98 KB

  wpack_kernel<<<24, 256, 0, stream>>>(W, Wf);
  qkv_kernel<<<dim3(HW / TP, NB), 256, 0, stream>>>(x, Wf, qkvb);
  attn_kernel<<<dim3(WDIM / 32, HDIM / 4, NB * HEADS), dim3(64, 4, 1), 0, stream>>>(qkvb, out);
}